// Round 1
// baseline (62.949 us; speedup 1.0000x reference)
//
#include <hip/hip_runtime.h>
#include <hip/hip_bf16.h>

#define NN 50000      // nodes
#define EE 800000     // edges
#define KD 512        // IN_DIM
#define ND 256        // H*D

typedef __bf16 bf16x8 __attribute__((ext_vector_type(8)));
typedef float f32x4 __attribute__((ext_vector_type(4)));

// fire-and-forget 16B global->LDS copy (dest = wave-uniform base + lane*16)
#define GLD16(g, l) __builtin_amdgcn_global_load_lds( \
    (const __attribute__((address_space(1))) unsigned int*)(g), \
    (__attribute__((address_space(3))) unsigned int*)(l), 16, 0, 0)

// ---------- Kernel 1: fused  (a) W (512x256 f32) -> Wt (256x512 bf16 [n][k])
//                             (b) zero the flags array ----------
__global__ __launch_bounds__(256) void prep_kernel(const float* __restrict__ W,
                                                   __hip_bfloat16* __restrict__ Wt,
                                                   unsigned char* __restrict__ flags) {
    if (blockIdx.x >= 32) {
        int idx = (blockIdx.x - 32) * 256 + threadIdx.x;
        if (idx < 3125) reinterpret_cast<uint4*>(flags)[idx] = (uint4){0, 0, 0, 0};
        return;
    }
    __shared__ __align__(16) __hip_bfloat16 tile[64][72];
    const int bk = blockIdx.x & 7;
    const int bn = blockIdx.x >> 3;
    const int k0 = bk * 64, n0 = bn * 64;
    const int t = threadIdx.x;
    const int r = t >> 2;
    const int c = (t & 3) * 16;
    const float4* src = reinterpret_cast<const float4*>(W + (size_t)(k0 + r) * ND + n0 + c);
#pragma unroll
    for (int i = 0; i < 4; ++i) {
        float4 f = src[i];
        tile[c + i * 4 + 0][r] = __float2bfloat16(f.x);
        tile[c + i * 4 + 1][r] = __float2bfloat16(f.y);
        tile[c + i * 4 + 2][r] = __float2bfloat16(f.z);
        tile[c + i * 4 + 3][r] = __float2bfloat16(f.w);
    }
    __syncthreads();
    uint4* dst = reinterpret_cast<uint4*>(Wt + (size_t)(n0 + r) * KD + k0 + c);
    dst[0] = *reinterpret_cast<const uint4*>(&tile[r][c]);
    dst[1] = *reinterpret_cast<const uint4*>(&tile[r][c + 8]);
}

// ---------- Kernel 2: flags[dst[e]] = 1 via test-and-set ----------
__global__ __launch_bounds__(256) void flag_set_kernel(const int* __restrict__ dst_idx,
                                                       unsigned char* __restrict__ flags) {
    int i = (blockIdx.x * 256 + threadIdx.x) * 4;
    if (i >= EE) return;  // EE % 4 == 0
    int4 d = *reinterpret_cast<const int4*>(dst_idx + i);
    if (flags[d.x] == 0) flags[d.x] = 1;
    if (flags[d.y] == 0) flags[d.y] = 1;
    if (flags[d.z] == 0) flags[d.z] = 1;
    if (flags[d.w] == 0) flags[d.w] = 1;
}

__device__ __forceinline__ bf16x8 cvt8(f32x4 lo, f32x4 hi) {
    union { __hip_bfloat16 h[8]; bf16x8 v; } u;
    u.h[0] = __float2bfloat16(lo[0]); u.h[1] = __float2bfloat16(lo[1]);
    u.h[2] = __float2bfloat16(lo[2]); u.h[3] = __float2bfloat16(lo[3]);
    u.h[4] = __float2bfloat16(hi[0]); u.h[5] = __float2bfloat16(hi[1]);
    u.h[6] = __float2bfloat16(hi[2]); u.h[7] = __float2bfloat16(hi[3]);
    return u.v;
}

// ---------- Kernel 3: out[m][n] = flags[m] ? (x @ W)[m][n] : 0 ----------
// BM=64, BN=128, BK=64. 256 threads = 4 waves (2M x 2N), wave tile 32x64,
// acc[2][4] of 16x16x32 bf16 MFMA.
// All staging is global_load_lds (fire-and-forget): A staged as RAW f32
// (f32->bf16 conversion at consume time), B as bf16 from Wt.
// Double-buffered LDS + counted s_waitcnt vmcnt(8): next k-step's loads stay
// in flight across the barrier, hidden under MFMA (raw s_barrier, NOT
// __syncthreads which drains vmcnt(0)).
// Bank conflicts: linear LDS dest (required by global_load_lds) + XOR-swizzled
// per-lane GLOBAL source address + same XOR on the ds_read side:
//   A (f32, 256B rows):  c ^= (row&7)<<5   (32B granule)
//   B (bf16, 128B rows): c ^= (row&7)<<4   (16B granule)
// Quarter-wave fragment reads then touch each bank exactly 2x (free).
__global__ __launch_bounds__(256, 2) void gemm_mask_kernel(const float* __restrict__ x,
                                                           const __hip_bfloat16* __restrict__ Wt,
                                                           const unsigned char* __restrict__ flags,
                                                           float* __restrict__ out) {
    __shared__ __align__(16) char As[2][16384];   // 64 rows x 64 k f32, dbuf
    __shared__ __align__(16) char Bs[2][16384];   // 128 rows x 64 k bf16, dbuf

    const int t = threadIdx.x;
    const int w = t >> 6;             // wave 0..3
    const int l = t & 63;
    const int mt = blockIdx.x >> 1;
    const int nt = blockIdx.x & 1;
    const int m_base = mt * 64;
    const int n0 = nt * 128;

    // ---- staging source pointers (per-lane, swizzled) ----
    const char* aSrc[4];
    const char* bSrc[4];
#pragma unroll
    for (int i = 0; i < 4; ++i) {
        // A: chunk (w*4+i) = 1024B = 4 rows of 256B; lane -> row +(l>>4), col (l&15)*16
        int arow = w * 16 + i * 4 + (l >> 4);
        int m = m_base + arow; if (m > NN - 1) m = NN - 1;  // clamp (stores guarded)
        int ac = ((l & 15) * 16) ^ ((arow & 7) << 5);
        aSrc[i] = (const char*)x + (size_t)m * (KD * 4) + ac;
        // B: chunk = 8 rows of 128B; lane -> row +(l>>3), col (l&7)*16
        int brow = w * 32 + i * 8 + (l >> 3);
        int bc = ((l & 7) * 16) ^ ((brow & 7) << 4);
        bSrc[i] = (const char*)Wt + (size_t)(n0 + brow) * (KD * 2) + bc;
    }

    // ---- consume-side per-lane LDS byte offsets (swizzled) ----
    const int wm = w >> 1, wn = w & 1;
    int aRd[2], bRd[2];
#pragma unroll
    for (int s = 0; s < 2; ++s) {
        int row = wm * 32 + (l & 15);                 // row&7 == l&7
        int c = s * 128 + (l >> 4) * 32;
        aRd[s] = row * 256 + (c ^ ((l & 7) << 5));
        int rowb = wn * 64 + (l & 15);                // row&7 == l&7
        int cb = s * 64 + (l >> 4) * 16;
        bRd[s] = rowb * 128 + (cb ^ ((l & 7) << 4));
    }

    f32x4 acc[2][4];
#pragma unroll
    for (int i = 0; i < 2; ++i)
#pragma unroll
        for (int j = 0; j < 4; ++j) acc[i][j] = (f32x4){0.f, 0.f, 0.f, 0.f};

    // ---- prologue: stage kt=0 into buf0 (8 loads/wave in flight) ----
#pragma unroll
    for (int i = 0; i < 4; ++i) {
        GLD16(aSrc[i], &As[0][(w * 4 + i) * 1024]);
        GLD16(bSrc[i], &Bs[0][(w * 4 + i) * 1024]);
    }

#pragma unroll
    for (int kt = 0; kt < 8; ++kt) {
        const int cur = kt & 1;
        if (kt < 7) {
            // issue next k-step's loads (into the buffer computed last iter;
            // end-of-iter barrier below guarantees everyone finished reading it)
#pragma unroll
            for (int i = 0; i < 4; ++i) {
                GLD16(aSrc[i] + (kt + 1) * 256, &As[cur ^ 1][(w * 4 + i) * 1024]);
                GLD16(bSrc[i] + (kt + 1) * 128, &Bs[cur ^ 1][(w * 4 + i) * 1024]);
            }
            asm volatile("s_waitcnt vmcnt(8)" ::: "memory");  // kt's data landed; 8 stay in flight
        } else {
            asm volatile("s_waitcnt vmcnt(0)" ::: "memory");
        }
        __builtin_amdgcn_s_barrier();

#pragma unroll
        for (int s = 0; s < 2; ++s) {
            bf16x8 afr[2], bfr[4];
#pragma unroll
            for (int tm = 0; tm < 2; ++tm) {
                const char* p = &As[cur][aRd[s] + tm * 4096];
                f32x4 lo = *reinterpret_cast<const f32x4*>(p);
                f32x4 hi = *reinterpret_cast<const f32x4*>(p + 16);
                afr[tm] = cvt8(lo, hi);
            }
#pragma unroll
            for (int tn = 0; tn < 4; ++tn)
                bfr[tn] = *reinterpret_cast<const bf16x8*>(&Bs[cur][bRd[s] + tn * 2048]);
#pragma unroll
            for (int tm = 0; tm < 2; ++tm)
#pragma unroll
                for (int tn = 0; tn < 4; ++tn)
                    acc[tm][tn] = __builtin_amdgcn_mfma_f32_16x16x32_bf16(afr[tm], bfr[tn], acc[tm][tn], 0, 0, 0);
        }
        __builtin_amdgcn_s_barrier();   // all waves done reading buf[cur]
    }

    // ---- epilogue: C/D layout col=lane&15, row=(lane>>4)*4+r ----
    const int col = l & 15;
    const int rq = (l >> 4) * 4;
#pragma unroll
    for (int tm = 0; tm < 2; ++tm) {
#pragma unroll
        for (int r = 0; r < 4; ++r) {
            const int m = m_base + wm * 32 + tm * 16 + rq + r;
            if (m < NN) {
                const float fl = (float)flags[m];
                float* orow = out + (size_t)m * ND + n0 + wn * 64 + col;
#pragma unroll
                for (int tn = 0; tn < 4; ++tn)
                    orow[tn * 16] = acc[tm][tn][r] * fl;
            }
        }
    }
}

extern "C" void kernel_launch(void* const* d_in, const int* in_sizes, int n_in,
                              void* d_out, int out_size, void* d_ws, size_t ws_size,
                              hipStream_t stream) {
    const float* x = (const float*)d_in[0];          // (N, 512) f32
    const int* edge_index = (const int*)d_in[1];     // (2, E) i32: row0=src, row1=dst
    const float* W = (const float*)d_in[3];          // (512, 256) f32
    float* out = (float*)d_out;                      // (N, 256) f32

    unsigned char* flags = (unsigned char*)d_ws;                       // NN bytes (16B-aligned)
    __hip_bfloat16* Wt = (__hip_bfloat16*)((char*)d_ws + 65536);       // 256 KB

    prep_kernel<<<45, 256, 0, stream>>>(W, Wt, flags);
    flag_set_kernel<<<(EE / 4 + 255) / 256, 256, 0, stream>>>(edge_index + EE, flags);
    gemm_mask_kernel<<<2 * ((NN + 63) / 64), 256, 0, stream>>>(x, Wt, flags, out);
}